// Round 13
// baseline (224.021 us; speedup 1.0000x reference)
//
#include <hip/hip_runtime.h>

#define NN 100000
#define CC 128
#define HHEADS 8
#define EE 1600000
#define NB 196          // buckets of 512 nodes
#define BCAP 10240      // bucket capacity (mean 8192, +22 sigma)
#define BSTRIDE 16      // bucketCnt padded to one per 64B line
#define P1C 3125        // edges per p1 block (512 * 3125 = EE exactly)

typedef unsigned short u16;
typedef unsigned int u32;
typedef __attribute__((ext_vector_type(8))) u16 u16x8;
typedef __attribute__((ext_vector_type(4))) u16 u16x4;
typedef __attribute__((ext_vector_type(8))) __bf16 bf16x8;
typedef __attribute__((ext_vector_type(4))) float f32x4;
typedef __attribute__((ext_vector_type(2))) float f32x2;

__device__ __forceinline__ float bf2f(u16 u) {
    union { u32 i; float f; } v; v.i = ((u32)u) << 16; return v.f;
}
__device__ __forceinline__ u16 f2bf(float f) {
    union { float f; u32 i; } v; v.f = f;
    u32 r = v.i + 0x7FFFu + ((v.i >> 16) & 1u);
    return (u16)(r >> 16);
}
__device__ __forceinline__ float fexp2(float x) {
    float r;
    asm volatile("v_exp_f32 %0, %1" : "=v"(r) : "v"(x));
    return r;
}

__device__ __forceinline__ f32x4 mfma16(u16x8 a, u16x8 b, f32x4 c) {
    return __builtin_amdgcn_mfma_f32_16x16x32_bf16(
        __builtin_bit_cast(bf16x8, a), __builtin_bit_cast(bf16x8, b), c, 0, 0, 0);
}

#define GLOAD(gp, lp) __builtin_amdgcn_global_load_lds( \
    (const __attribute__((address_space(1))) u32*)(gp), \
    (__attribute__((address_space(3))) u32*)(lp), 16, 0, 0)

// ---------------- pre: p1 edge-bucketing + x0 cvt + weight cvts (one launch) --------
__global__ __launch_bounds__(256) void k_pre(
    const int* __restrict__ src, const int* __restrict__ dst,
    int* __restrict__ bucketCnt, u32* __restrict__ bucketEdges,
    const float* __restrict__ x0, u16* __restrict__ x0b,
    const float* __restrict__ s0, const float* __restrict__ s1,
    const float* __restrict__ s2, const float* __restrict__ s3,
    const float* __restrict__ s4,
    u16* __restrict__ d0, u16* __restrict__ d1, u16* __restrict__ d2,
    u16* __restrict__ d3, u16* __restrict__ d4)
{
    const int b = blockIdx.x, tid = threadIdx.x;
    if (b < 512) {
        __shared__ u32 s_src[P1C];
        __shared__ u32 s_dst[P1C];
        __shared__ u32 hist[256], ssum[256], bstart[256], base[256], seq[256];
        const int beg = b * P1C;

        hist[tid] = 0; seq[tid] = 0;
        __syncthreads();

        int es[13], ds[13];
#pragma unroll
        for (int j = 0; j < 13; j++) {
            int o = tid + j * 256;
            if (o < P1C) { es[j] = src[beg + o]; ds[j] = dst[beg + o]; }
            else { es[j] = -1; ds[j] = 0; }
        }
#pragma unroll
        for (int j = 0; j < 13; j++)
            if (es[j] >= 0) atomicAdd(&hist[(u32)ds[j] >> 9], 1u);
        __syncthreads();

        u32 h = hist[tid];
        ssum[tid] = h;
        __syncthreads();
        for (int o = 1; o < 256; o <<= 1) {
            u32 v = ssum[tid];
            u32 a = (tid >= o) ? ssum[tid - o] : 0;
            __syncthreads();
            ssum[tid] = v + a;
            __syncthreads();
        }
        bstart[tid] = ssum[tid] - h;
        if (tid < NB) base[tid] = h ? (u32)atomicAdd(&bucketCnt[tid * BSTRIDE], (int)h) : 0u;
        __syncthreads();

#pragma unroll
        for (int j = 0; j < 13; j++) {
            if (es[j] >= 0) {
                u32 bb = (u32)ds[j] >> 9;
                u32 r = atomicAdd(&seq[bb], 1u);
                u32 pos = bstart[bb] + r;
                s_src[pos] = (u32)es[j];
                s_dst[pos] = (u32)ds[j];
            }
        }
        __syncthreads();

        for (int i = tid; i < P1C; i += 256) {
            u32 d = s_dst[i];
            u32 bb = d >> 9;
            u32 go = base[bb] + ((u32)i - bstart[bb]);
            if (go < BCAP)
                bucketEdges[(size_t)bb * BCAP + go] = s_src[i] | ((d & 511u) << 17);
        }
    } else if (b < 2560) {
        const int n = NN * CC;
        const int stride = 2048 * 256 * 4;
        for (int i = ((b - 512) * 256 + tid) * 4; i < n; i += stride) {
            float4 v = *(const float4*)(x0 + i);
            u16x4 o;
            o.x = f2bf(v.x); o.y = f2bf(v.y); o.z = f2bf(v.z); o.w = f2bf(v.w);
            *(u16x4*)(x0b + i) = o;
        }
    } else {
        int wb = b - 2560;
        const float* s; u16* d; int boff;
        if (wb < 16)      { s = s0; d = d0; boff = wb; }
        else if (wb < 32) { s = s1; d = d1; boff = wb - 16; }
        else if (wb < 48) { s = s2; d = d2; boff = wb - 32; }
        else if (wb < 80) { s = s3; d = d3; boff = wb - 48; }
        else              { s = s4; d = d4; boff = wb - 80; }
        int i = boff * 1024 + tid * 4;
        float4 v = *(const float4*)(s + i);
        u16x4 o;
        o.x = f2bf(v.x); o.y = f2bf(v.y); o.z = f2bf(v.z); o.w = f2bf(v.w);
        *(u16x4*)(d + i) = o;
    }
}

// ---------------- pass 2: per-bucket CSR build ----------------
__global__ __launch_bounds__(256) void k_p2(const int* __restrict__ bucketCnt,
                                            u32* __restrict__ bucketEdges,
                                            int* __restrict__ offs,
                                            int* __restrict__ cnt)
{
    __shared__ u32 ebuf[BCAP];
    __shared__ u32 ncnt[512], loff[512], ssum[256];
    const int b = blockIdx.x, tid = threadIdx.x;
    int n = bucketCnt[b * BSTRIDE]; n = n < BCAP ? n : BCAP;
    u32* be = bucketEdges + (size_t)b * BCAP;

    for (int i = tid; i < n; i += 256) ebuf[i] = be[i];
    ncnt[tid] = 0; ncnt[tid + 256] = 0;
    __syncthreads();
    for (int i = tid; i < n; i += 256) atomicAdd(&ncnt[(ebuf[i] >> 17) & 511], 1u);
    __syncthreads();

    u32 a0 = ncnt[2 * tid], a1 = ncnt[2 * tid + 1];
    ssum[tid] = a0 + a1;
    __syncthreads();
    for (int o = 1; o < 256; o <<= 1) {
        u32 v = ssum[tid];
        u32 add = (tid >= o) ? ssum[tid - o] : 0;
        __syncthreads();
        ssum[tid] = v + add;
        __syncthreads();
    }
    u32 excl = ssum[tid] - (a0 + a1);
    loff[2 * tid] = excl;
    loff[2 * tid + 1] = excl + a0;

    int node0 = b * 512 + 2 * tid;
    if (node0 < NN)     { offs[node0]     = b * BCAP + (int)excl;            cnt[node0]     = (int)a0; }
    if (node0 + 1 < NN) { offs[node0 + 1] = b * BCAP + (int)(excl + a0);     cnt[node0 + 1] = (int)a1; }

    ncnt[tid] = 0; ncnt[tid + 256] = 0;
    __syncthreads();
    for (int i = tid; i < n; i += 256) {
        u32 e = ebuf[i];
        u32 ln = (e >> 17) & 511;
        u32 r = atomicAdd(&ncnt[ln], 1u);
        be[loff[ln] + r] = e & 0x1FFFFu;
    }
}

// ---------------- bf16 MFMA GEMM, BK=64, 4 blocks/CU, slim LN / split-out options ----
template<int K, bool BIAS, bool RELU, bool RESIDB, bool LNF, bool SPLIT>
__global__ __launch_bounds__(256, 4) void k_gemm(
    const u16* __restrict__ A, const u16* __restrict__ B,
    const float* __restrict__ bias, const u16* __restrict__ residb,
    const float* __restrict__ g, const float* __restrict__ bln,
    float* __restrict__ outf, u16* __restrict__ outb, u16* __restrict__ outbB,
    int M, int NC)
{
    __shared__ __align__(16) u16 As[128 * 64];
    __shared__ __align__(16) u16 Bs[128 * 64];
    __shared__ float lsum[2][128], lsq[2][128];

    const int tid = threadIdx.x;
    const int lane = tid & 63;
    const int w = tid >> 6;
    const int wr = w >> 1, wc = w & 1;
    const int row0 = blockIdx.x * 128;
    const int col0 = blockIdx.y * 128;
    f32x4 acc[4][4] = {};

    for (int kt = 0; kt < K; kt += 64) {
#pragma unroll
        for (int i = 0; i < 4; i++) {
            int c = i * 256 + tid;
            int r = c >> 3;
            int kc = (c & 7) * 8;
            int ar = row0 + r; ar = ar < M ? ar : M - 1;
            GLOAD(A + (size_t)ar * K + kt + kc, As + r * 64 + kc);
            GLOAD(B + (size_t)(col0 + r) * K + kt + kc, Bs + r * 64 + kc);
        }
        asm volatile("s_waitcnt vmcnt(0)" ::: "memory");
        __syncthreads();
#pragma unroll
        for (int kk = 0; kk < 2; kk++) {
            const int ko = kk * 32 + (lane >> 4) * 8;
            u16x8 af[4], bfr[4];
#pragma unroll
            for (int m = 0; m < 4; m++)
                af[m] = *(const u16x8*)(As + (wr * 64 + m * 16 + (lane & 15)) * 64 + ko);
#pragma unroll
            for (int n = 0; n < 4; n++)
                bfr[n] = *(const u16x8*)(Bs + (wc * 64 + n * 16 + (lane & 15)) * 64 + ko);
#pragma unroll
            for (int m = 0; m < 4; m++)
#pragma unroll
                for (int n = 0; n < 4; n++)
                    acc[m][n] = mfma16(af[m], bfr[n], acc[m][n]);
        }
        __syncthreads();
    }

    const int rbase = wr * 64 + ((lane >> 4) << 2);
    const int cbase = wc * 64 + (lane & 15);

    if constexpr (!LNF) {
        u16* ob = outb;
        if constexpr (SPLIT) ob = col0 ? outbB : outb;
#pragma unroll
        for (int m = 0; m < 4; m++) {
#pragma unroll
            for (int j = 0; j < 4; j++) {
                int gr = row0 + rbase + m * 16 + j;
                if (gr < M) {
                    size_t rowoff = (size_t)gr * NC;
#pragma unroll
                    for (int n = 0; n < 4; n++) {
                        int gc = (SPLIT ? 0 : col0) + cbase + n * 16;
                        float v = acc[m][n][j];
                        if constexpr (BIAS)  v += bias[col0 + cbase + n * 16];
                        if constexpr (RELU)  v = fmaxf(v, 0.f);
                        if (outf) outf[rowoff + gc] = v;
                        if (ob) ob[rowoff + gc] = f2bf(v);
                    }
                }
            }
        }
    } else {
        float gv[4], bv[4];
#pragma unroll
        for (int n = 0; n < 4; n++) { gv[n] = g[cbase + n * 16]; bv[n] = bln[cbase + n * 16]; }
#pragma unroll
        for (int m = 0; m < 4; m++) {
#pragma unroll
            for (int j = 0; j < 4; j++) {
                int lr = rbase + m * 16 + j;
                int gr = row0 + lr; gr = gr < M ? gr : M - 1;
                float s = 0.f, q = 0.f;
#pragma unroll
                for (int n = 0; n < 4; n++) {
                    float v = acc[m][n][j];
                    if constexpr (BIAS)   v += bias[cbase + n * 16];
                    if constexpr (RESIDB) v += bf2f(residb[(size_t)gr * 128 + cbase + n * 16]);
                    if constexpr (RELU)   v = fmaxf(v, 0.f);
                    acc[m][n][j] = v;
                    s += v; q += v * v;
                }
                s += __shfl_xor(s, 1, 16); q += __shfl_xor(q, 1, 16);
                s += __shfl_xor(s, 2, 16); q += __shfl_xor(q, 2, 16);
                s += __shfl_xor(s, 4, 16); q += __shfl_xor(q, 4, 16);
                s += __shfl_xor(s, 8, 16); q += __shfl_xor(q, 8, 16);
                if ((lane & 15) == 0) { lsum[wc][lr] = s; lsq[wc][lr] = q; }
            }
        }
        __syncthreads();
#pragma unroll
        for (int m = 0; m < 4; m++) {
#pragma unroll
            for (int j = 0; j < 4; j++) {
                int lr = rbase + m * 16 + j;
                int gr = row0 + lr;
                if (gr < M) {
                    float s = lsum[0][lr] + lsum[1][lr];
                    float q = lsq[0][lr] + lsq[1][lr];
                    float mu = s * (1.f / 128.f);
                    float var = q * (1.f / 128.f) - mu * mu;
                    float rs = rsqrtf(var + 1e-5f);
                    size_t rowoff = (size_t)gr * 128;
#pragma unroll
                    for (int n = 0; n < 4; n++) {
                        float y = fmaf((acc[m][n][j] - mu) * rs, gv[n], bv[n]);
                        int gc = cbase + n * 16;
                        if (outf) outf[rowoff + gc] = y;
                        if (outb) outb[rowoff + gc] = f2bf(y);
                    }
                }
            }
        }
    }
}

// ---------------- fused MLP v2 (R12 winner, unchanged) ------------------------------
__global__ __launch_bounds__(256, 2) void k_mlp(
    const u16* __restrict__ x3b, const u16* __restrict__ W1,
    const float* __restrict__ mb1, const u16* __restrict__ W2,
    const float* __restrict__ mb2, const float* __restrict__ g2,
    const float* __restrict__ b2, float* __restrict__ out, int M)
{
    __shared__ __align__(16) u16 x3s[128 * 128];
    __shared__ __align__(16) u16 hs[128 * 130];
    __shared__ float lsum[2][128], lsq[2][128];

    const int tid = threadIdx.x;
    const int lane = tid & 63;
    const int w = tid >> 6;
    const int wr = w >> 1, wc = w & 1;
    const int row0 = blockIdx.x * 128;
    const int rbase = wr * 64 + ((lane >> 4) << 2);
    const int cbase = wc * 64 + (lane & 15);

#pragma unroll
    for (int i = 0; i < 8; i++) {
        int c = i * 256 + tid;
        int r = c >> 4;
        int kc = (c & 15) * 8;
        int ar = row0 + r; ar = ar < M ? ar : M - 1;
        GLOAD(x3b + (size_t)ar * 128 + kc, x3s + r * 128 + kc);
    }
    asm volatile("s_waitcnt vmcnt(0)" ::: "memory");
    __syncthreads();

    f32x4 accB[4][4] = {};
    for (int half = 0; half < 2; half++) {
        f32x4 accA[4][4] = {};
#pragma unroll
        for (int kk = 0; kk < 4; kk++) {
            const int ko = kk * 32 + (lane >> 4) * 8;
            u16x8 af[4], bfr[4];
#pragma unroll
            for (int m = 0; m < 4; m++)
                af[m] = *(const u16x8*)(x3s + (wr * 64 + m * 16 + (lane & 15)) * 128 + ko);
#pragma unroll
            for (int n = 0; n < 4; n++)
                bfr[n] = *(const u16x8*)(W1 + (size_t)(half * 128 + wc * 64 + n * 16 + (lane & 15)) * 128 + ko);
#pragma unroll
            for (int m = 0; m < 4; m++)
#pragma unroll
                for (int n = 0; n < 4; n++)
                    accA[m][n] = mfma16(af[m], bfr[n], accA[m][n]);
        }
        float bv[4];
#pragma unroll
        for (int n = 0; n < 4; n++) bv[n] = mb1[half * 128 + cbase + n * 16];
#pragma unroll
        for (int m = 0; m < 4; m++)
#pragma unroll
            for (int n = 0; n < 4; n++) {
                int lc = cbase + n * 16;
#pragma unroll
                for (int j = 0; j < 4; j++) {
                    float v = fmaxf(accA[m][n][j] + bv[n], 0.f);
                    hs[(rbase + m * 16 + j) * 130 + lc] = f2bf(v);
                }
            }
        __syncthreads();

#pragma unroll
        for (int kk = 0; kk < 4; kk++) {
            const int ko = kk * 32 + (lane >> 4) * 8;
            u16x8 af[4], bfr[4];
#pragma unroll
            for (int m = 0; m < 4; m++)
                af[m] = *(const u16x8*)(hs + (wr * 64 + m * 16 + (lane & 15)) * 130 + ko);
#pragma unroll
            for (int n = 0; n < 4; n++)
                bfr[n] = *(const u16x8*)(W2 + (size_t)(wc * 64 + n * 16 + (lane & 15)) * 256 + half * 128 + ko);
#pragma unroll
            for (int m = 0; m < 4; m++)
#pragma unroll
                for (int n = 0; n < 4; n++)
                    accB[m][n] = mfma16(af[m], bfr[n], accB[m][n]);
        }
        __syncthreads();
    }

    float gv[4], bvln[4], bv2[4];
#pragma unroll
    for (int n = 0; n < 4; n++) {
        gv[n] = g2[cbase + n * 16];
        bvln[n] = b2[cbase + n * 16];
        bv2[n] = mb2[cbase + n * 16];
    }
#pragma unroll
    for (int m = 0; m < 4; m++) {
#pragma unroll
        for (int j = 0; j < 4; j++) {
            int lr = rbase + m * 16 + j;
            float s = 0.f, q = 0.f;
#pragma unroll
            for (int n = 0; n < 4; n++) {
                float v = accB[m][n][j] + bv2[n] + bf2f(x3s[lr * 128 + cbase + n * 16]);
                accB[m][n][j] = v;
                s += v; q += v * v;
            }
            s += __shfl_xor(s, 1, 16); q += __shfl_xor(q, 1, 16);
            s += __shfl_xor(s, 2, 16); q += __shfl_xor(q, 2, 16);
            s += __shfl_xor(s, 4, 16); q += __shfl_xor(q, 4, 16);
            s += __shfl_xor(s, 8, 16); q += __shfl_xor(q, 8, 16);
            if ((lane & 15) == 0) { lsum[wc][lr] = s; lsq[wc][lr] = q; }
        }
    }
    __syncthreads();
#pragma unroll
    for (int m = 0; m < 4; m++) {
#pragma unroll
        for (int j = 0; j < 4; j++) {
            int lr = rbase + m * 16 + j;
            int gr = row0 + lr;
            if (gr < M) {
                float s = lsum[0][lr] + lsum[1][lr];
                float q = lsq[0][lr] + lsq[1][lr];
                float mu = s * (1.f / 128.f);
                float var = q * (1.f / 128.f) - mu * mu;
                float rs = rsqrtf(var + 1e-5f);
                size_t rowoff = (size_t)gr * 128;
#pragma unroll
                for (int n = 0; n < 4; n++)
                    out[rowoff + cbase + n * 16] =
                        fmaf((accB[m][n][j] - mu) * rs, gv[n], bvln[n]);
            }
        }
    }
}

// ---------------- GAT aggregation: split xl/xr, 3-deep prefetch, junk->row0 ---------
// Out-of-range prefetches redirect to row 0 (L1-hot chip-wide) instead of a
// random clamped row -- removes ~50-75% junk gather traffic that killed R10.
__global__ __launch_bounds__(256) void k_gat(const u16* __restrict__ xlb,
                                             const u16* __restrict__ xrb,
                                             const u32* __restrict__ csr,
                                             const int* __restrict__ offs,
                                             const int* __restrict__ cnt,
                                             const float* __restrict__ att,
                                             const float* __restrict__ gbias,
                                             u16* __restrict__ x1b)
{
    const int node = blockIdx.x * 4 + (threadIdx.x >> 6);
    const int lane = threadIdx.x & 63;
    const int slot = lane >> 4;          // 0..3 edge stream
    const int sub  = lane & 15;          // 8-channel chunk
    const int c0   = sub * 8;
    const float L2E = 1.44269504f;

    f32x4 alo = *(const f32x4*)(att + c0);
    f32x4 ahi = *(const f32x4*)(att + c0 + 4);
    f32x2 av[4];
    av[0] = f32x2{alo[0], alo[1]} * L2E; av[1] = f32x2{alo[2], alo[3]} * L2E;
    av[2] = f32x2{ahi[0], ahi[1]} * L2E; av[3] = f32x2{ahi[2], ahi[3]} * L2E;

    u16x8 xr8 = *(const u16x8*)(xrb + (size_t)node * 128 + c0);
    f32x2 xrv[4];
#pragma unroll
    for (int j = 0; j < 4; j++) xrv[j] = f32x2{bf2f(xr8[2 * j]), bf2f(xr8[2 * j + 1])};

    const int beg = offs[node];
    const int deg = cnt[node];
    const int ng = (deg + 3) >> 2;
    const int dm1 = deg - 1;

    auto idxof = [&](int gi) -> int {
        if (gi >= ng) return 0;                       // junk -> row 0 (L1-hot)
        int en = 4 * gi + slot; en = en < dm1 ? en : dm1;
        return (int)csr[beg + en];
    };
    auto rowld = [&](int ix) -> u16x8 {
        return *(const u16x8*)(xlb + (size_t)ix * 128 + c0);
    };

    float s = 0.f;
    f32x2 accv[4] = {};

    u16x8 xgA = {}, xgB = {}, xgC = {};
    int ixD = 0;
    if (deg > 0) {
        xgA = rowld(idxof(0));
        xgB = rowld(idxof(1));
        xgC = rowld(idxof(2));
        ixD = idxof(3);
    }

    for (int g = 0; g < ng; g++) {
        u16x8 cur = xgA;
        xgA = xgB;
        xgB = xgC;
        xgC = rowld(ixD);                // gather g+3
        ixD = idxof(g + 4);              // idx g+4

        const int e = 4 * g + slot;
        f32x2 xlv[4];
        f32x2 dot = {0.f, 0.f};
#pragma unroll
        for (int j = 0; j < 4; j++) {
            f32x2 xl = f32x2{bf2f(cur[2 * j]), bf2f(cur[2 * j + 1])};
            xlv[j] = xl;
            f32x2 t = xl + xrv[j];
            f32x2 t2 = t * 0.2f;
            f32x2 lr = f32x2{fmaxf(t.x, t2.x), fmaxf(t.y, t2.y)};
            dot += av[j] * lr;
        }
        float p = dot.x + dot.y;
        p += __shfl_xor(p, 1);                      // half-head partner
        float wgt = (e < deg) ? fexp2(p) : 0.f;     // no max subtraction needed
        s += wgt;
#pragma unroll
        for (int j = 0; j < 4; j++) accv[j] += xlv[j] * wgt;
    }

    s += __shfl_xor(s, 16);
    s += __shfl_xor(s, 32);
#pragma unroll
    for (int j = 0; j < 4; j++) {
        accv[j].x += __shfl_xor(accv[j].x, 16);
        accv[j].y += __shfl_xor(accv[j].y, 16);
        accv[j].x += __shfl_xor(accv[j].x, 32);
        accv[j].y += __shfl_xor(accv[j].y, 32);
    }

    if (slot == 0) {
        float inv = 1.f / (s + 1e-16f);
        u16x8 o;
#pragma unroll
        for (int j = 0; j < 4; j++) {
            o[2 * j]     = f2bf(fmaf(accv[j].x, inv, gbias[c0 + 2 * j]));
            o[2 * j + 1] = f2bf(fmaf(accv[j].y, inv, gbias[c0 + 2 * j + 1]));
        }
        *(u16x8*)(x1b + (size_t)node * CC + c0) = o;
    }
}

extern "C" void kernel_launch(void* const* d_in, const int* in_sizes, int n_in,
                              void* d_out, int out_size, void* d_ws, size_t ws_size,
                              hipStream_t stream) {
    const float* x0    = (const float*)d_in[0];
    const int*   edges = (const int*)d_in[1];      // [2,E]: src row, dst row
    const float* lin_l = (const float*)d_in[2];
    const float* lin_r = (const float*)d_in[3];
    const float* att   = (const float*)d_in[4];
    const float* gbias = (const float*)d_in[5];
    const float* Ww    = (const float*)d_in[6];
    const float* g1    = (const float*)d_in[7];
    const float* b1    = (const float*)d_in[8];
    const float* w1    = (const float*)d_in[9];
    const float* mb1   = (const float*)d_in[10];
    const float* w2    = (const float*)d_in[11];
    const float* mb2   = (const float*)d_in[12];
    const float* g2    = (const float*)d_in[13];
    const float* b2    = (const float*)d_in[14];
    float* out = (float*)d_out;

    char* ws = (char*)d_ws;
    size_t off = 0;
    auto alloc = [&](size_t bytes) {
        char* p = ws + off;
        off += (bytes + 255) & ~(size_t)255;
        return p;
    };
    u16*   x0b   = (u16*)alloc((size_t)NN * CC * 2);      // reused as x3b
    u16*   xlb   = (u16*)alloc((size_t)NN * 128 * 2);     // gather target (dense)
    u16*   xrb   = (u16*)alloc((size_t)NN * 128 * 2);
    u16*   x1b   = (u16*)alloc((size_t)NN * CC * 2);
    u16*   Wa    = (u16*)alloc(256 * 128 * 2);            // [lin_l ; lin_r]
    u16*   Wb    = (u16*)alloc(128 * 128 * 2);
    u16*   W1    = (u16*)alloc(256 * 128 * 2);
    u16*   W2    = (u16*)alloc(128 * 256 * 2);
    int*   bucketCnt   = (int*)alloc((size_t)NB * BSTRIDE * 4);
    u32*   bucketEdges = (u32*)alloc((size_t)NB * BCAP * 4);
    int*   offsA       = (int*)alloc((size_t)NN * 4);
    int*   cntA        = (int*)alloc((size_t)NN * 4);
    u16*   x3b = x0b;
    (void)in_sizes; (void)n_in; (void)out_size; (void)ws_size;

    // 1) zero bucket counters + fused {p1 bucketing, x0 cvt, weight cvts}
    hipMemsetAsync(bucketCnt, 0, (size_t)NB * BSTRIDE * 4, stream);
    k_pre<<<2672, 256, 0, stream>>>(edges, edges + EE, bucketCnt, bucketEdges,
                                    x0, x0b, lin_l, lin_r, Ww, w1, w2,
                                    Wa, Wa + 16384, Wb, W1, W2);

    // 2) per-bucket CSR
    k_p2<<<NB, 256, 0, stream>>>(bucketCnt, bucketEdges, offsA, cntA);

    // 3) stage-1 GEMM: xl = x0@lin_l^T -> xlb, xr = x0@lin_r^T -> xrb (split out)
    k_gemm<128, false, false, false, false, true><<<dim3(782, 2), 256, 0, stream>>>(
        x0b, Wa, nullptr, nullptr, nullptr, nullptr, nullptr, xlb, xrb, NN, 128);

    // 4) GAT aggregation -> x1 bf16
    k_gat<<<NN / 4, 256, 0, stream>>>(xlb, xrb, bucketEdges, offsA, cntA, att, gbias, x1b);

    // 5+6) x3 = LN(x1 @ W^T + x0)  fused -> x3b bf16
    k_gemm<128, false, false, true, true, false><<<dim3(782, 1), 256, 0, stream>>>(
        x1b, Wb, nullptr, x0b, g1, b1, nullptr, x3b, nullptr, NN, 128);

    // 7+8+9) out = LN(relu(x3@W1^T+b1)@W2^T + b2 + x3)  fused MLP v2
    k_mlp<<<782, 256, 0, stream>>>(x3b, W1, mb1, W2, mb2, g2, b2, out, NN);
}

// Round 14
// 211.829 us; speedup vs baseline: 1.0576x; 1.0576x over previous
//
#include <hip/hip_runtime.h>

#define NN 100000
#define CC 128
#define HHEADS 8
#define EE 1600000
#define NB 196          // buckets of 512 nodes
#define BCAP 10240      // bucket capacity (mean 8192, +22 sigma)
#define BSTRIDE 16      // bucketCnt padded to one per 64B line
#define P1C 3125        // edges per p1 block (512 * 3125 = EE exactly)

typedef unsigned short u16;
typedef unsigned int u32;
typedef __attribute__((ext_vector_type(8))) u16 u16x8;
typedef __attribute__((ext_vector_type(4))) u16 u16x4;
typedef __attribute__((ext_vector_type(8))) __bf16 bf16x8;
typedef __attribute__((ext_vector_type(4))) float f32x4;
typedef __attribute__((ext_vector_type(2))) float f32x2;

__device__ __forceinline__ float bf2f(u16 u) {
    union { u32 i; float f; } v; v.i = ((u32)u) << 16; return v.f;
}
__device__ __forceinline__ u16 f2bf(float f) {
    union { float f; u32 i; } v; v.f = f;
    u32 r = v.i + 0x7FFFu + ((v.i >> 16) & 1u);
    return (u16)(r >> 16);
}
__device__ __forceinline__ float fexp2(float x) {
    float r;
    asm volatile("v_exp_f32 %0, %1" : "=v"(r) : "v"(x));
    return r;
}

__device__ __forceinline__ f32x4 mfma16(u16x8 a, u16x8 b, f32x4 c) {
    return __builtin_amdgcn_mfma_f32_16x16x32_bf16(
        __builtin_bit_cast(bf16x8, a), __builtin_bit_cast(bf16x8, b), c, 0, 0, 0);
}

#define GLOAD(gp, lp) __builtin_amdgcn_global_load_lds( \
    (const __attribute__((address_space(1))) u32*)(gp), \
    (__attribute__((address_space(3))) u32*)(lp), 16, 0, 0)

// ---------------- pre: p1 edge-bucketing + x0 cvt + weight cvts (one launch) --------
__global__ __launch_bounds__(256) void k_pre(
    const int* __restrict__ src, const int* __restrict__ dst,
    int* __restrict__ bucketCnt, u32* __restrict__ bucketEdges,
    const float* __restrict__ x0, u16* __restrict__ x0b,
    const float* __restrict__ s0, const float* __restrict__ s1,
    const float* __restrict__ s2, const float* __restrict__ s3,
    const float* __restrict__ s4,
    u16* __restrict__ d0, u16* __restrict__ d1, u16* __restrict__ d2,
    u16* __restrict__ d3, u16* __restrict__ d4)
{
    const int b = blockIdx.x, tid = threadIdx.x;
    if (b < 512) {
        __shared__ u32 s_src[P1C];
        __shared__ u32 s_dst[P1C];
        __shared__ u32 hist[256], ssum[256], bstart[256], base[256], seq[256];
        const int beg = b * P1C;

        hist[tid] = 0; seq[tid] = 0;
        __syncthreads();

        int es[13], ds[13];
#pragma unroll
        for (int j = 0; j < 13; j++) {
            int o = tid + j * 256;
            if (o < P1C) { es[j] = src[beg + o]; ds[j] = dst[beg + o]; }
            else { es[j] = -1; ds[j] = 0; }
        }
#pragma unroll
        for (int j = 0; j < 13; j++)
            if (es[j] >= 0) atomicAdd(&hist[(u32)ds[j] >> 9], 1u);
        __syncthreads();

        u32 h = hist[tid];
        ssum[tid] = h;
        __syncthreads();
        for (int o = 1; o < 256; o <<= 1) {
            u32 v = ssum[tid];
            u32 a = (tid >= o) ? ssum[tid - o] : 0;
            __syncthreads();
            ssum[tid] = v + a;
            __syncthreads();
        }
        bstart[tid] = ssum[tid] - h;
        if (tid < NB) base[tid] = h ? (u32)atomicAdd(&bucketCnt[tid * BSTRIDE], (int)h) : 0u;
        __syncthreads();

#pragma unroll
        for (int j = 0; j < 13; j++) {
            if (es[j] >= 0) {
                u32 bb = (u32)ds[j] >> 9;
                u32 r = atomicAdd(&seq[bb], 1u);
                u32 pos = bstart[bb] + r;
                s_src[pos] = (u32)es[j];
                s_dst[pos] = (u32)ds[j];
            }
        }
        __syncthreads();

        for (int i = tid; i < P1C; i += 256) {
            u32 d = s_dst[i];
            u32 bb = d >> 9;
            u32 go = base[bb] + ((u32)i - bstart[bb]);
            if (go < BCAP)
                bucketEdges[(size_t)bb * BCAP + go] = s_src[i] | ((d & 511u) << 17);
        }
    } else if (b < 2560) {
        const int n = NN * CC;
        const int stride = 2048 * 256 * 4;
        for (int i = ((b - 512) * 256 + tid) * 4; i < n; i += stride) {
            float4 v = *(const float4*)(x0 + i);
            u16x4 o;
            o.x = f2bf(v.x); o.y = f2bf(v.y); o.z = f2bf(v.z); o.w = f2bf(v.w);
            *(u16x4*)(x0b + i) = o;
        }
    } else {
        int wb = b - 2560;
        const float* s; u16* d; int boff;
        if (wb < 16)      { s = s0; d = d0; boff = wb; }
        else if (wb < 32) { s = s1; d = d1; boff = wb - 16; }
        else if (wb < 48) { s = s2; d = d2; boff = wb - 32; }
        else if (wb < 80) { s = s3; d = d3; boff = wb - 48; }
        else              { s = s4; d = d4; boff = wb - 80; }
        int i = boff * 1024 + tid * 4;
        float4 v = *(const float4*)(s + i);
        u16x4 o;
        o.x = f2bf(v.x); o.y = f2bf(v.y); o.z = f2bf(v.z); o.w = f2bf(v.w);
        *(u16x4*)(d + i) = o;
    }
}

// ---------------- pass 2: per-bucket CSR build ----------------
__global__ __launch_bounds__(256) void k_p2(const int* __restrict__ bucketCnt,
                                            u32* __restrict__ bucketEdges,
                                            int* __restrict__ offs,
                                            int* __restrict__ cnt)
{
    __shared__ u32 ebuf[BCAP];
    __shared__ u32 ncnt[512], loff[512], ssum[256];
    const int b = blockIdx.x, tid = threadIdx.x;
    int n = bucketCnt[b * BSTRIDE]; n = n < BCAP ? n : BCAP;
    u32* be = bucketEdges + (size_t)b * BCAP;

    for (int i = tid; i < n; i += 256) ebuf[i] = be[i];
    ncnt[tid] = 0; ncnt[tid + 256] = 0;
    __syncthreads();
    for (int i = tid; i < n; i += 256) atomicAdd(&ncnt[(ebuf[i] >> 17) & 511], 1u);
    __syncthreads();

    u32 a0 = ncnt[2 * tid], a1 = ncnt[2 * tid + 1];
    ssum[tid] = a0 + a1;
    __syncthreads();
    for (int o = 1; o < 256; o <<= 1) {
        u32 v = ssum[tid];
        u32 add = (tid >= o) ? ssum[tid - o] : 0;
        __syncthreads();
        ssum[tid] = v + add;
        __syncthreads();
    }
    u32 excl = ssum[tid] - (a0 + a1);
    loff[2 * tid] = excl;
    loff[2 * tid + 1] = excl + a0;

    int node0 = b * 512 + 2 * tid;
    if (node0 < NN)     { offs[node0]     = b * BCAP + (int)excl;            cnt[node0]     = (int)a0; }
    if (node0 + 1 < NN) { offs[node0 + 1] = b * BCAP + (int)(excl + a0);     cnt[node0 + 1] = (int)a1; }

    ncnt[tid] = 0; ncnt[tid + 256] = 0;
    __syncthreads();
    for (int i = tid; i < n; i += 256) {
        u32 e = ebuf[i];
        u32 ln = (e >> 17) & 511;
        u32 r = atomicAdd(&ncnt[ln], 1u);
        be[loff[ln] + r] = e & 0x1FFFFu;
    }
}

// ---------------- bf16 MFMA GEMM, BK=64, 4 blocks/CU (stage-1 only) -----------------
template<int K>
__global__ __launch_bounds__(256, 4) void k_gemm(
    const u16* __restrict__ A, const u16* __restrict__ B,
    u16* __restrict__ outb, int M, int NC)
{
    __shared__ __align__(16) u16 As[128 * 64];
    __shared__ __align__(16) u16 Bs[128 * 64];

    const int tid = threadIdx.x;
    const int lane = tid & 63;
    const int w = tid >> 6;
    const int wr = w >> 1, wc = w & 1;
    const int row0 = blockIdx.x * 128;
    const int col0 = blockIdx.y * 128;
    f32x4 acc[4][4] = {};

    for (int kt = 0; kt < K; kt += 64) {
#pragma unroll
        for (int i = 0; i < 4; i++) {
            int c = i * 256 + tid;
            int r = c >> 3;
            int kc = (c & 7) * 8;
            int ar = row0 + r; ar = ar < M ? ar : M - 1;
            GLOAD(A + (size_t)ar * K + kt + kc, As + r * 64 + kc);
            GLOAD(B + (size_t)(col0 + r) * K + kt + kc, Bs + r * 64 + kc);
        }
        asm volatile("s_waitcnt vmcnt(0)" ::: "memory");
        __syncthreads();
#pragma unroll
        for (int kk = 0; kk < 2; kk++) {
            const int ko = kk * 32 + (lane >> 4) * 8;
            u16x8 af[4], bfr[4];
#pragma unroll
            for (int m = 0; m < 4; m++)
                af[m] = *(const u16x8*)(As + (wr * 64 + m * 16 + (lane & 15)) * 64 + ko);
#pragma unroll
            for (int n = 0; n < 4; n++)
                bfr[n] = *(const u16x8*)(Bs + (wc * 64 + n * 16 + (lane & 15)) * 64 + ko);
#pragma unroll
            for (int m = 0; m < 4; m++)
#pragma unroll
                for (int n = 0; n < 4; n++)
                    acc[m][n] = mfma16(af[m], bfr[n], acc[m][n]);
        }
        __syncthreads();
    }

    const int rbase = wr * 64 + ((lane >> 4) << 2);
    const int cbase = wc * 64 + (lane & 15);
#pragma unroll
    for (int m = 0; m < 4; m++) {
#pragma unroll
        for (int j = 0; j < 4; j++) {
            int gr = row0 + rbase + m * 16 + j;
            if (gr < M) {
                size_t rowoff = (size_t)gr * NC;
#pragma unroll
                for (int n = 0; n < 4; n++) {
                    int gc = col0 + cbase + n * 16;
                    outb[rowoff + gc] = f2bf(acc[m][n][j]);
                }
            }
        }
    }
}

// ---------------- fused tail: out = LN2(relu(LN1(x1@Wb^T+x0)@W1^T+b1)@W2^T+b2+x3) ---
// 128-row slab, 67.3 KB LDS -> 2 blocks/CU. Wb/W1/W2 B-frags direct from global
// (L2-broadcast). bufA: x1 -> x3 (in place). bufB: x0 (stride 128) -> hs (stride 130).
__global__ __launch_bounds__(256, 2) void k_tail(
    const u16* __restrict__ x1b, const u16* __restrict__ Wb,
    const u16* __restrict__ x0b, const float* __restrict__ g1,
    const float* __restrict__ b1, const u16* __restrict__ W1,
    const float* __restrict__ mb1, const u16* __restrict__ W2,
    const float* __restrict__ mb2, const float* __restrict__ g2,
    const float* __restrict__ b2, float* __restrict__ out, int M)
{
    __shared__ __align__(16) u16 bufA[128 * 128];  // 32 KB: x1, then x3
    __shared__ __align__(16) u16 bufB[128 * 130];  // 33.3 KB: x0 (s128), then hs (s130)
    __shared__ float lsum[2][128], lsq[2][128];    // 2 KB

    const int tid = threadIdx.x;
    const int lane = tid & 63;
    const int w = tid >> 6;
    const int wr = w >> 1, wc = w & 1;
    const int row0 = blockIdx.x * 128;
    const int rbase = wr * 64 + ((lane >> 4) << 2);
    const int cbase = wc * 64 + (lane & 15);

    // ---- stage x1 + x0 slabs ----
#pragma unroll
    for (int i = 0; i < 8; i++) {
        int c = i * 256 + tid;
        int r = c >> 4;
        int kc = (c & 15) * 8;
        int ar = row0 + r; ar = ar < M ? ar : M - 1;
        GLOAD(x1b + (size_t)ar * 128 + kc, bufA + r * 128 + kc);
        GLOAD(x0b + (size_t)ar * 128 + kc, bufB + r * 128 + kc);
    }
    asm volatile("s_waitcnt vmcnt(0)" ::: "memory");
    __syncthreads();

    // ---- GEMM: accW = x1 @ Wb^T (B-frags direct from global) ----
    f32x4 accW[4][4] = {};
#pragma unroll
    for (int kk = 0; kk < 4; kk++) {
        const int ko = kk * 32 + (lane >> 4) * 8;
        u16x8 af[4], bfr[4];
#pragma unroll
        for (int m = 0; m < 4; m++)
            af[m] = *(const u16x8*)(bufA + (wr * 64 + m * 16 + (lane & 15)) * 128 + ko);
#pragma unroll
        for (int n = 0; n < 4; n++)
            bfr[n] = *(const u16x8*)(Wb + (size_t)(wc * 64 + n * 16 + (lane & 15)) * 128 + ko);
#pragma unroll
        for (int m = 0; m < 4; m++)
#pragma unroll
            for (int n = 0; n < 4; n++)
                accW[m][n] = mfma16(af[m], bfr[n], accW[m][n]);
    }

    // ---- LN1 stats: v = accW + x0 ----
#pragma unroll
    for (int m = 0; m < 4; m++) {
#pragma unroll
        for (int j = 0; j < 4; j++) {
            int lr = rbase + m * 16 + j;
            float s = 0.f, q = 0.f;
#pragma unroll
            for (int n = 0; n < 4; n++) {
                float v = accW[m][n][j] + bf2f(bufB[lr * 128 + cbase + n * 16]);
                accW[m][n][j] = v;
                s += v; q += v * v;
            }
            s += __shfl_xor(s, 1, 16); q += __shfl_xor(q, 1, 16);
            s += __shfl_xor(s, 2, 16); q += __shfl_xor(q, 2, 16);
            s += __shfl_xor(s, 4, 16); q += __shfl_xor(q, 4, 16);
            s += __shfl_xor(s, 8, 16); q += __shfl_xor(q, 8, 16);
            if ((lane & 15) == 0) { lsum[wc][lr] = s; lsq[wc][lr] = q; }
        }
    }
    __syncthreads();   // all GEMM A-reads + x0 reads done; lsum/lsq visible

    // ---- x3 = LN1 -> bufA (in place over dead x1) ----
    {
        float gv[4], bv[4];
#pragma unroll
        for (int n = 0; n < 4; n++) { gv[n] = g1[cbase + n * 16]; bv[n] = b1[cbase + n * 16]; }
#pragma unroll
        for (int m = 0; m < 4; m++) {
#pragma unroll
            for (int j = 0; j < 4; j++) {
                int lr = rbase + m * 16 + j;
                float s = lsum[0][lr] + lsum[1][lr];
                float q = lsq[0][lr] + lsq[1][lr];
                float mu = s * (1.f / 128.f);
                float var = q * (1.f / 128.f) - mu * mu;
                float rs = rsqrtf(var + 1e-5f);
#pragma unroll
                for (int n = 0; n < 4; n++)
                    bufA[lr * 128 + cbase + n * 16] =
                        f2bf(fmaf((accW[m][n][j] - mu) * rs, gv[n], bv[n]));
            }
        }
    }
    __syncthreads();   // x3 visible to all waves; bufB (x0) now dead

    // ---- MLP: two halves, hs overlays bufB with stride 130 ----
    f32x4 accB[4][4] = {};
    for (int half = 0; half < 2; half++) {
        f32x4 accA[4][4] = {};
#pragma unroll
        for (int kk = 0; kk < 4; kk++) {
            const int ko = kk * 32 + (lane >> 4) * 8;
            u16x8 af[4], bfr[4];
#pragma unroll
            for (int m = 0; m < 4; m++)
                af[m] = *(const u16x8*)(bufA + (wr * 64 + m * 16 + (lane & 15)) * 128 + ko);
#pragma unroll
            for (int n = 0; n < 4; n++)
                bfr[n] = *(const u16x8*)(W1 + (size_t)(half * 128 + wc * 64 + n * 16 + (lane & 15)) * 128 + ko);
#pragma unroll
            for (int m = 0; m < 4; m++)
#pragma unroll
                for (int n = 0; n < 4; n++)
                    accA[m][n] = mfma16(af[m], bfr[n], accA[m][n]);
        }
        float bv[4];
#pragma unroll
        for (int n = 0; n < 4; n++) bv[n] = mb1[half * 128 + cbase + n * 16];
#pragma unroll
        for (int m = 0; m < 4; m++)
#pragma unroll
            for (int n = 0; n < 4; n++) {
                int lc = cbase + n * 16;
#pragma unroll
                for (int j = 0; j < 4; j++) {
                    float v = fmaxf(accA[m][n][j] + bv[n], 0.f);
                    bufB[(rbase + m * 16 + j) * 130 + lc] = f2bf(v);
                }
            }
        __syncthreads();   // hs ready

#pragma unroll
        for (int kk = 0; kk < 4; kk++) {
            const int ko = kk * 32 + (lane >> 4) * 8;
            u16x8 af[4], bfr[4];
#pragma unroll
            for (int m = 0; m < 4; m++)
                af[m] = *(const u16x8*)(bufB + (wr * 64 + m * 16 + (lane & 15)) * 130 + ko);
#pragma unroll
            for (int n = 0; n < 4; n++)
                bfr[n] = *(const u16x8*)(W2 + (size_t)(wc * 64 + n * 16 + (lane & 15)) * 256 + half * 128 + ko);
#pragma unroll
            for (int m = 0; m < 4; m++)
#pragma unroll
                for (int n = 0; n < 4; n++)
                    accB[m][n] = mfma16(af[m], bfr[n], accB[m][n]);
        }
        __syncthreads();   // hs reads done before next half overwrites
    }

    // ---- LN2 epilogue: v = accB + b2m + x3(bufA) ----
    float gv[4], bvln[4], bv2[4];
#pragma unroll
    for (int n = 0; n < 4; n++) {
        gv[n] = g2[cbase + n * 16];
        bvln[n] = b2[cbase + n * 16];
        bv2[n] = mb2[cbase + n * 16];
    }
#pragma unroll
    for (int m = 0; m < 4; m++) {
#pragma unroll
        for (int j = 0; j < 4; j++) {
            int lr = rbase + m * 16 + j;
            float s = 0.f, q = 0.f;
#pragma unroll
            for (int n = 0; n < 4; n++) {
                float v = accB[m][n][j] + bv2[n] + bf2f(bufA[lr * 128 + cbase + n * 16]);
                accB[m][n][j] = v;
                s += v; q += v * v;
            }
            s += __shfl_xor(s, 1, 16); q += __shfl_xor(q, 1, 16);
            s += __shfl_xor(s, 2, 16); q += __shfl_xor(q, 2, 16);
            s += __shfl_xor(s, 4, 16); q += __shfl_xor(q, 4, 16);
            s += __shfl_xor(s, 8, 16); q += __shfl_xor(q, 8, 16);
            if ((lane & 15) == 0) { lsum[wc][lr] = s; lsq[wc][lr] = q; }
        }
    }
    __syncthreads();
#pragma unroll
    for (int m = 0; m < 4; m++) {
#pragma unroll
        for (int j = 0; j < 4; j++) {
            int lr = rbase + m * 16 + j;
            int gr = row0 + lr;
            if (gr < M) {
                float s = lsum[0][lr] + lsum[1][lr];
                float q = lsq[0][lr] + lsq[1][lr];
                float mu = s * (1.f / 128.f);
                float var = q * (1.f / 128.f) - mu * mu;
                float rs = rsqrtf(var + 1e-5f);
                size_t rowoff = (size_t)gr * 128;
#pragma unroll
                for (int n = 0; n < 4; n++)
                    out[rowoff + cbase + n * 16] =
                        fmaf((accB[m][n][j] - mu) * rs, gv[n], bvln[n]);
            }
        }
    }
}

// ---------------- GAT aggregation: no-max softmax, 2-deep prefetch (R11/R12 winner) --
__global__ __launch_bounds__(256) void k_gat(const u16* __restrict__ xlr,
                                             const u32* __restrict__ csr,
                                             const int* __restrict__ offs,
                                             const int* __restrict__ cnt,
                                             const float* __restrict__ att,
                                             const float* __restrict__ gbias,
                                             u16* __restrict__ x1b)
{
    const int node = blockIdx.x * 4 + (threadIdx.x >> 6);
    const int lane = threadIdx.x & 63;
    const int slot = lane >> 4;          // 0..3 edge stream
    const int sub  = lane & 15;          // 8-channel chunk
    const int c0   = sub * 8;
    const float L2E = 1.44269504f;

    f32x4 alo = *(const f32x4*)(att + c0);
    f32x4 ahi = *(const f32x4*)(att + c0 + 4);
    f32x2 av[4];
    av[0] = f32x2{alo[0], alo[1]} * L2E; av[1] = f32x2{alo[2], alo[3]} * L2E;
    av[2] = f32x2{ahi[0], ahi[1]} * L2E; av[3] = f32x2{ahi[2], ahi[3]} * L2E;

    u16x8 xr8 = *(const u16x8*)(xlr + (size_t)node * 256 + 128 + c0);
    f32x2 xrv[4];
#pragma unroll
    for (int j = 0; j < 4; j++) xrv[j] = f32x2{bf2f(xr8[2 * j]), bf2f(xr8[2 * j + 1])};

    const int beg = offs[node];
    const int deg = cnt[node];
    const int ng = (deg + 3) >> 2;

    float s = 0.f;
    f32x2 accv[4] = {};

    u16x8 xgA = {}, xgB = {};
    int ixC = 0;
    if (deg > 0) {
        int dm1 = deg - 1;
        int e0 = slot      < dm1 ? slot      : dm1;
        int e1 = slot + 4  < dm1 ? slot + 4  : dm1;
        int e2 = slot + 8  < dm1 ? slot + 8  : dm1;
        int i0 = (int)csr[beg + e0];
        int i1 = (int)csr[beg + e1];
        ixC    = (int)csr[beg + e2];
        xgA = *(const u16x8*)(xlr + (size_t)i0 * 256 + c0);
        xgB = *(const u16x8*)(xlr + (size_t)i1 * 256 + c0);
    }

    for (int g = 0; g < ng; g++) {
        u16x8 cur = xgA;
        xgA = xgB;
        xgB = *(const u16x8*)(xlr + (size_t)ixC * 256 + c0);
        int en = 4 * (g + 3) + slot; en = en < deg - 1 ? en : deg - 1;
        ixC = (int)csr[beg + (en > 0 ? en : 0)];

        const int e = 4 * g + slot;
        f32x2 xlv[4];
        f32x2 dot = {0.f, 0.f};
#pragma unroll
        for (int j = 0; j < 4; j++) {
            f32x2 xl = f32x2{bf2f(cur[2 * j]), bf2f(cur[2 * j + 1])};
            xlv[j] = xl;
            f32x2 t = xl + xrv[j];
            f32x2 t2 = t * 0.2f;
            f32x2 lr = f32x2{fmaxf(t.x, t2.x), fmaxf(t.y, t2.y)};
            dot += av[j] * lr;
        }
        float p = dot.x + dot.y;
        p += __shfl_xor(p, 1);                      // half-head partner
        float wgt = (e < deg) ? fexp2(p) : 0.f;     // no max subtraction needed
        s += wgt;
#pragma unroll
        for (int j = 0; j < 4; j++) accv[j] += xlv[j] * wgt;
    }

    s += __shfl_xor(s, 16);
    s += __shfl_xor(s, 32);
#pragma unroll
    for (int j = 0; j < 4; j++) {
        accv[j].x += __shfl_xor(accv[j].x, 16);
        accv[j].y += __shfl_xor(accv[j].y, 16);
        accv[j].x += __shfl_xor(accv[j].x, 32);
        accv[j].y += __shfl_xor(accv[j].y, 32);
    }

    if (slot == 0) {
        float inv = 1.f / (s + 1e-16f);
        u16x8 o;
#pragma unroll
        for (int j = 0; j < 4; j++) {
            o[2 * j]     = f2bf(fmaf(accv[j].x, inv, gbias[c0 + 2 * j]));
            o[2 * j + 1] = f2bf(fmaf(accv[j].y, inv, gbias[c0 + 2 * j + 1]));
        }
        *(u16x8*)(x1b + (size_t)node * CC + c0) = o;
    }
}

extern "C" void kernel_launch(void* const* d_in, const int* in_sizes, int n_in,
                              void* d_out, int out_size, void* d_ws, size_t ws_size,
                              hipStream_t stream) {
    const float* x0    = (const float*)d_in[0];
    const int*   edges = (const int*)d_in[1];      // [2,E]: src row, dst row
    const float* lin_l = (const float*)d_in[2];
    const float* lin_r = (const float*)d_in[3];
    const float* att   = (const float*)d_in[4];
    const float* gbias = (const float*)d_in[5];
    const float* Ww    = (const float*)d_in[6];
    const float* g1    = (const float*)d_in[7];
    const float* b1    = (const float*)d_in[8];
    const float* w1    = (const float*)d_in[9];
    const float* mb1   = (const float*)d_in[10];
    const float* w2    = (const float*)d_in[11];
    const float* mb2   = (const float*)d_in[12];
    const float* g2    = (const float*)d_in[13];
    const float* b2    = (const float*)d_in[14];
    float* out = (float*)d_out;

    char* ws = (char*)d_ws;
    size_t off = 0;
    auto alloc = [&](size_t bytes) {
        char* p = ws + off;
        off += (bytes + 255) & ~(size_t)255;
        return p;
    };
    u16*   x0b   = (u16*)alloc((size_t)NN * CC * 2);
    u16*   xlr   = (u16*)alloc((size_t)NN * 256 * 2);
    u16*   x1b   = (u16*)alloc((size_t)NN * CC * 2);
    u16*   Wa    = (u16*)alloc(256 * 128 * 2);            // [lin_l ; lin_r]
    u16*   Wb    = (u16*)alloc(128 * 128 * 2);
    u16*   W1    = (u16*)alloc(256 * 128 * 2);
    u16*   W2    = (u16*)alloc(128 * 256 * 2);
    int*   bucketCnt   = (int*)alloc((size_t)NB * BSTRIDE * 4);
    u32*   bucketEdges = (u32*)alloc((size_t)NB * BCAP * 4);
    int*   offsA       = (int*)alloc((size_t)NN * 4);
    int*   cntA        = (int*)alloc((size_t)NN * 4);
    (void)in_sizes; (void)n_in; (void)out_size; (void)ws_size;

    // 1) zero bucket counters + fused {p1 bucketing, x0 cvt, weight cvts}
    hipMemsetAsync(bucketCnt, 0, (size_t)NB * BSTRIDE * 4, stream);
    k_pre<<<2672, 256, 0, stream>>>(edges, edges + EE, bucketCnt, bucketEdges,
                                    x0, x0b, lin_l, lin_r, Ww, w1, w2,
                                    Wa, Wa + 16384, Wb, W1, W2);

    // 2) per-bucket CSR
    k_p2<<<NB, 256, 0, stream>>>(bucketCnt, bucketEdges, offsA, cntA);

    // 3) stage-1 GEMM: [x_l | x_r] = x0 @ [lin_l;lin_r]^T  -> xlr bf16 [N,256]
    k_gemm<128><<<dim3(782, 2), 256, 0, stream>>>(x0b, Wa, xlr, NN, 256);

    // 4) GAT aggregation -> x1 bf16
    k_gat<<<NN / 4, 256, 0, stream>>>(xlr, bucketEdges, offsA, cntA, att, gbias, x1b);

    // 5..9) out = LN2(relu(LN1(x1@Ww^T+x0)@W1^T+b1)@W2^T+b2+x3)  fully fused tail
    k_tail<<<782, 256, 0, stream>>>(x1b, Wb, x0b, g1, b1, W1, mb1, W2, mb2,
                                    g2, b2, out, NN);
}